// Round 6
// baseline (225.568 us; speedup 1.0000x reference)
//
#include <hip/hip_runtime.h>
#include <hip/hip_bf16.h>
#include <cstddef>
#include <cstdint>

#define Bb 4
#define Tt 1024
#define Dd 1024
#define Hh 16

typedef __bf16 bf16x8 __attribute__((ext_vector_type(8)));
typedef __bf16 bf16x4 __attribute__((ext_vector_type(4)));
typedef float  f32x4  __attribute__((ext_vector_type(4)));

__device__ __forceinline__ void gload16(const void* g, void* l) {
    __builtin_amdgcn_global_load_lds(
        (const __attribute__((address_space(1))) void*)g,
        (__attribute__((address_space(3))) void*)l, 16, 0, 0);
}

// ---------------------------------------------------------------------------
// Fused prep: [0,4096) cast x -> bf16; [4096,4864) Wqkv transpose;
// [4864,5120) Wproj transpose.
// ---------------------------------------------------------------------------
__global__ __launch_bounds__(256) void prep(const float* __restrict__ x,
                                            const float* __restrict__ Wqkv,
                                            const float* __restrict__ Wproj,
                                            __bf16* __restrict__ xb,
                                            __bf16* __restrict__ wqT,
                                            __bf16* __restrict__ wpT) {
    const int bid = blockIdx.x;
    if (bid < 4096) {  // cast
        int i = bid * 256 + threadIdx.x;
        float4 v = ((const float4*)x)[i];
        bf16x4 o = { (__bf16)v.x, (__bf16)v.y, (__bf16)v.z, (__bf16)v.w };
        ((bf16x4*)xb)[i] = o;
        return;
    }
    __shared__ float ld[64][65];
    const float* in;
    __bf16* out;
    int K, N, k0, n0;
    if (bid < 4096 + 768) {
        int j = bid - 4096;
        in = Wqkv; out = wqT; K = 1024; N = 3072;
        k0 = (j & 15) * 64; n0 = (j >> 4) * 64;
    } else {
        int j = bid - 4096 - 768;
        in = Wproj; out = wpT; K = 1024; N = 1024;
        k0 = (j & 15) * 64; n0 = (j >> 4) * 64;
    }
    #pragma unroll
    for (int i = 0; i < 16; i++) {
        int idx = i * 256 + threadIdx.x;
        int r = idx >> 6, c = idx & 63;
        ld[r][c] = in[(size_t)(k0 + r) * N + n0 + c];
    }
    __syncthreads();
    #pragma unroll
    for (int i = 0; i < 16; i++) {
        int idx = i * 256 + threadIdx.x;
        int r = idx >> 6, c = idx & 63;
        out[(size_t)(n0 + r) * K + k0 + c] = (__bf16)ld[c][r];
    }
}

// ---------------------------------------------------------------------------
// V slice of qkv [b][t][3072] (cols 2048 + h*64 + d) -> vt [b][h][d][t] bf16
// ---------------------------------------------------------------------------
__global__ __launch_bounds__(256) void v_transpose(const __bf16* __restrict__ qkv,
                                                   __bf16* __restrict__ vt) {
    __shared__ __bf16 ld[64][65];
    const int t0 = blockIdx.x * 64;
    const int h  = blockIdx.y;
    const int b  = blockIdx.z;
    const size_t src = ((size_t)(b * Tt + t0)) * 3072 + 2048 + h * 64;
    #pragma unroll
    for (int i = 0; i < 16; i++) {
        int idx = i * 256 + threadIdx.x;
        int tr = idx >> 6, dc = idx & 63;
        ld[tr][dc] = qkv[src + (size_t)tr * 3072 + dc];
    }
    __syncthreads();
    const size_t dst = ((size_t)((b * Hh + h) * 64)) * Tt + t0;
    #pragma unroll
    for (int i = 0; i < 16; i++) {
        int idx = i * 256 + threadIdx.x;
        int dr = idx >> 6, tc = idx & 63;
        vt[dst + (size_t)dr * Tt + tc] = ld[tc][dr];
    }
}

// ---------------------------------------------------------------------------
// 128x128 MFMA GEMM, BK=64, XOR-8 swizzled LDS. C = A @ Bt^T + bias.
// mode 0: fp32 out. mode 1 (qkv): bf16 out, cols<1024 scaled by 0.125.
// ---------------------------------------------------------------------------
__global__ __launch_bounds__(256) void gemm_bf16(const __bf16* __restrict__ A,
                                                 const __bf16* __restrict__ Bt,
                                                 const float* __restrict__ bias,
                                                 void* __restrict__ Cout,
                                                 int M, int N, int K, int mode) {
    __shared__ __align__(16) __bf16 As[128 * 64];
    __shared__ __align__(16) __bf16 Bs[128 * 64];
    const int tid  = threadIdx.x;
    const int lane = tid & 63;
    const int wave = tid >> 6;
    const int wy = wave >> 1, wx = wave & 1;
    const int l15 = lane & 15, quad = lane >> 4;
    const size_t row0 = (size_t)blockIdx.y * 128;
    const size_t col0 = (size_t)blockIdx.x * 128;

    f32x4 acc[4][4] = {};

    for (int k0 = 0; k0 < K; k0 += 64) {
        #pragma unroll
        for (int i = 0; i < 4; i++) {
            int c = i * 256 + tid;
            int r = c >> 3, seg = (c & 7) ^ (r & 7);
            gload16(&A[(row0 + r) * K + k0 + seg * 8], &As[c * 8]);
        }
        #pragma unroll
        for (int i = 0; i < 4; i++) {
            int c = i * 256 + tid;
            int r = c >> 3, seg = (c & 7) ^ (r & 7);
            gload16(&Bt[(col0 + r) * K + k0 + seg * 8], &Bs[c * 8]);
        }
        __syncthreads();
        #pragma unroll
        for (int kc = 0; kc < 2; kc++) {
            bf16x8 af[4], bfr[4];
            #pragma unroll
            for (int i = 0; i < 4; i++)
                af[i] = *(const bf16x8*)&As[(wy * 64 + i * 16 + l15) * 64 +
                                            (((kc * 4 + quad) ^ (l15 & 7)) * 8)];
            #pragma unroll
            for (int j = 0; j < 4; j++)
                bfr[j] = *(const bf16x8*)&Bs[(wx * 64 + j * 16 + l15) * 64 +
                                             (((kc * 4 + quad) ^ (l15 & 7)) * 8)];
            #pragma unroll
            for (int i = 0; i < 4; i++)
                #pragma unroll
                for (int j = 0; j < 4; j++)
                    acc[i][j] = __builtin_amdgcn_mfma_f32_16x16x32_bf16(af[i], bfr[j], acc[i][j], 0, 0, 0);
        }
        __syncthreads();
    }

    #pragma unroll
    for (int j = 0; j < 4; j++) {
        const size_t col = col0 + wx * 64 + j * 16 + l15;
        const float bj = bias[col];
        const float scale = (mode == 1 && col < 1024) ? 0.125f : 1.0f;
        #pragma unroll
        for (int i = 0; i < 4; i++) {
            const size_t row = row0 + wy * 64 + i * 16 + quad * 4;
            #pragma unroll
            for (int r = 0; r < 4; r++) {
                float v = (acc[i][j][r] + bj) * scale;
                if (mode == 1) ((__bf16*)Cout)[(row + r) * N + col] = (__bf16)v;
                else           ((float*)Cout)[(row + r) * N + col] = v;
            }
        }
    }
}

// ---------------------------------------------------------------------------
// 128x64-tile GEMM (proj), BK=64, swizzled. fp32 out.
// ---------------------------------------------------------------------------
__global__ __launch_bounds__(256) void gemm_bf16_n64(const __bf16* __restrict__ A,
                                                     const __bf16* __restrict__ Bt,
                                                     const float* __restrict__ bias,
                                                     float* __restrict__ Cout,
                                                     int M, int N, int K) {
    __shared__ __align__(16) __bf16 As[128 * 64];
    __shared__ __align__(16) __bf16 Bs[64 * 64];
    const int tid  = threadIdx.x;
    const int lane = tid & 63;
    const int wave = tid >> 6;
    const int wy = wave >> 1, wx = wave & 1;
    const int l15 = lane & 15, quad = lane >> 4;
    const size_t row0 = (size_t)blockIdx.y * 128;
    const size_t col0 = (size_t)blockIdx.x * 64;

    f32x4 acc[4][2] = {};

    for (int k0 = 0; k0 < K; k0 += 64) {
        #pragma unroll
        for (int i = 0; i < 4; i++) {
            int c = i * 256 + tid;
            int r = c >> 3, seg = (c & 7) ^ (r & 7);
            gload16(&A[(row0 + r) * K + k0 + seg * 8], &As[c * 8]);
        }
        #pragma unroll
        for (int i = 0; i < 2; i++) {
            int c = i * 256 + tid;
            int r = c >> 3, seg = (c & 7) ^ (r & 7);
            gload16(&Bt[(col0 + r) * K + k0 + seg * 8], &Bs[c * 8]);
        }
        __syncthreads();
        #pragma unroll
        for (int kc = 0; kc < 2; kc++) {
            bf16x8 af[4], bfr[2];
            #pragma unroll
            for (int i = 0; i < 4; i++)
                af[i] = *(const bf16x8*)&As[(wy * 64 + i * 16 + l15) * 64 +
                                            (((kc * 4 + quad) ^ (l15 & 7)) * 8)];
            #pragma unroll
            for (int j = 0; j < 2; j++)
                bfr[j] = *(const bf16x8*)&Bs[(wx * 32 + j * 16 + l15) * 64 +
                                             (((kc * 4 + quad) ^ (l15 & 7)) * 8)];
            #pragma unroll
            for (int i = 0; i < 4; i++)
                #pragma unroll
                for (int j = 0; j < 2; j++)
                    acc[i][j] = __builtin_amdgcn_mfma_f32_16x16x32_bf16(af[i], bfr[j], acc[i][j], 0, 0, 0);
        }
        __syncthreads();
    }

    #pragma unroll
    for (int j = 0; j < 2; j++) {
        const size_t col = col0 + wx * 32 + j * 16 + l15;
        const float bj = bias[col];
        #pragma unroll
        for (int i = 0; i < 4; i++) {
            const size_t row = row0 + wy * 64 + i * 16 + quad * 4;
            #pragma unroll
            for (int r = 0; r < 4; r++)
                Cout[(row + r) * N + col] = acc[i][j][r] + bj;
        }
    }
}

// ---------------------------------------------------------------------------
// Barrier-free flash attention (S^T = K @ Q^T form).
// Grid: (h + 16*b = 64, qt = 16) -> same (b,h) pinned to one XCD class for
// K/V L2 locality. Block = 4 waves; wave w owns Q rows qt*64 + w*16 .. +16.
// Q staged once through LDS (one barrier), frags preloaded to registers.
// K/V fragments read DIRECTLY from global each iter (L2-served, compiler
// emits fine-grained vmcnt). P round-trips through a PER-WAVE LDS strip that
// overlays the wave's own dead Q rows -> zero __syncthreads in the K-loop.
// ---------------------------------------------------------------------------
__global__ __launch_bounds__(256, 3) void attn_mfma(const __bf16* __restrict__ qkv,
                                                    const __bf16* __restrict__ vt,
                                                    const int* __restrict__ mask,
                                                    __bf16* __restrict__ att) {
    __shared__ __align__(16) __bf16 smem[64 * 64];  // Q stage; then per-wave Ps strips

    const int h  = blockIdx.x & 15;
    const int b  = blockIdx.x >> 4;
    const int qt = blockIdx.y;
    const int tid = threadIdx.x, lane = tid & 63, wave = tid >> 6;
    const int l15 = lane & 15, quad = lane >> 4;

    // ---- stage Q tile (swizzled 8-el chunks), one barrier, preload frags ----
    #pragma unroll
    for (int i = 0; i < 2; i++) {
        int c = i * 256 + tid;
        int rr = c >> 3, ch = c & 7;
        gload16(&qkv[((size_t)(b * Tt + qt * 64 + rr)) * 3072 + h * 64 + ((ch ^ (rr & 7)) * 8)],
                &smem[c * 8]);
    }
    __syncthreads();  // the only block barrier
    bf16x8 qf0 = *(const bf16x8*)&smem[(wave * 16 + l15) * 64 + ((quad ^ (l15 & 7)) * 8)];
    bf16x8 qf1 = *(const bf16x8*)&smem[(wave * 16 + l15) * 64 + (((4 + quad) ^ (l15 & 7)) * 8)];
    // wave's own Q rows == wave's Ps strip; wave-private from here on.
    __bf16* const Ps = &smem[wave * 1024];

    f32x4 Oacc[4] = {};
    float lsum = 0.0f;

    const size_t kbase = (size_t)b * Tt * 3072 + 1024 + h * 64;
    const size_t vbase = (size_t)((b * Hh + h) * 64) * Tt;

    for (int kt = 0; kt <= qt; kt++) {
        // K/V A-fragments straight from global (16 rows x 64B segments, L2-hot)
        bf16x8 ak[4][2], av[4][2];
        #pragma unroll
        for (int j = 0; j < 4; j++) {
            const size_t krow = kbase + (size_t)(kt * 64 + j * 16 + l15) * 3072 + quad * 8;
            ak[j][0] = *(const bf16x8*)&qkv[krow];
            ak[j][1] = *(const bf16x8*)&qkv[krow + 32];
            const size_t vrow = vbase + (size_t)(j * 16 + l15) * Tt + kt * 64 + quad * 8;
            av[j][0] = *(const bf16x8*)&vt[vrow];
            av[j][1] = *(const bf16x8*)&vt[vrow + 32];
        }
        int mv4[4][4];
        #pragma unroll
        for (int j = 0; j < 4; j++) {
            const int4 m4 = *(const int4*)&mask[b * Tt + kt * 64 + j * 16 + quad * 4];
            mv4[j][0] = m4.x; mv4[j][1] = m4.y; mv4[j][2] = m4.z; mv4[j][3] = m4.w;
        }

        // S^T tiles + exp + P store (per-wave LDS, lgkmcnt-ordered, no barrier)
        #pragma unroll
        for (int j = 0; j < 4; j++) {
            f32x4 st = {};
            st = __builtin_amdgcn_mfma_f32_16x16x32_bf16(ak[j][0], qf0, st, 0, 0, 0);
            st = __builtin_amdgcn_mfma_f32_16x16x32_bf16(ak[j][1], qf1, st, 0, 0, 0);
            bf16x4 pv;
            #pragma unroll
            for (int r = 0; r < 4; r++) {
                const int tloc = j * 16 + quad * 4 + r;
                bool keep = (mv4[j][r] != 0);
                if (kt == qt) keep = keep && (tloc <= wave * 16 + l15);
                const float pe = keep ? __expf(st[r]) : 0.0f;
                lsum += pe;
                pv[r] = (__bf16)pe;
            }
            *(bf16x4*)&Ps[l15 * 64 + (((j * 4 + quad) ^ ((l15 & 7) << 1)) * 4)] = pv;
        }
        bf16x8 p0 = *(const bf16x8*)&Ps[l15 * 64 + (((2 * quad) ^ ((l15 & 7) << 1)) * 4)];
        bf16x8 p1 = *(const bf16x8*)&Ps[l15 * 64 + (((2 * (4 + quad)) ^ ((l15 & 7) << 1)) * 4)];
        #pragma unroll
        for (int n = 0; n < 4; n++) {
            Oacc[n] = __builtin_amdgcn_mfma_f32_16x16x32_bf16(av[n][0], p0, Oacc[n], 0, 0, 0);
            Oacc[n] = __builtin_amdgcn_mfma_f32_16x16x32_bf16(av[n][1], p1, Oacc[n], 0, 0, 0);
        }
    }

    // epilogue: reduce l across quads, normalize, store (O^T: lane col = q)
    float lt = lsum;
    lt += __shfl_xor(lt, 16);
    lt += __shfl_xor(lt, 32);
    const float inv = 1.0f / lt;
    const int q = qt * 64 + wave * 16 + l15;
    #pragma unroll
    for (int n = 0; n < 4; n++) {
        bf16x4 o;
        #pragma unroll
        for (int r = 0; r < 4; r++) o[r] = (__bf16)(Oacc[n][r] * inv);
        *(bf16x4*)&att[((size_t)(b * Tt + q)) * Dd + h * 64 + n * 16 + quad * 4] = o;
    }
}

// ---------------------------------------------------------------------------
extern "C" void kernel_launch(void* const* d_in, const int* in_sizes, int n_in,
                              void* d_out, int out_size, void* d_ws, size_t ws_size,
                              hipStream_t stream) {
    const float* x     = (const float*)d_in[0];
    const float* Wqkv  = (const float*)d_in[1];
    const float* bqkv  = (const float*)d_in[2];
    const float* Wproj = (const float*)d_in[3];
    const float* bproj = (const float*)d_in[4];
    const int*   mask  = (const int*)d_in[5];
    float* out = (float*)d_out;

    __bf16* xb  = (__bf16*)d_ws;                         // 4096*1024
    __bf16* wqT = xb  + (size_t)4096 * 1024;             // 3072*1024
    __bf16* wpT = wqT + (size_t)3072 * 1024;             // 1024*1024
    __bf16* qkv = wpT + (size_t)1024 * 1024;             // 4096*3072
    __bf16* vt  = qkv + (size_t)4096 * 3072;             // 4*16*64*1024
    __bf16* att = vt  + (size_t)4 * 16 * 64 * 1024;      // 4096*1024

    prep<<<4096 + 768 + 256, 256, 0, stream>>>(x, Wqkv, Wproj, xb, wqT, wpT);

    gemm_bf16<<<dim3(24, 32), 256, 0, stream>>>(xb, wqT, bqkv, qkv, 4096, 3072, 1024, 1);

    v_transpose<<<dim3(16, 16, 4), 256, 0, stream>>>(qkv, vt);
    attn_mfma<<<dim3(64, 16), 256, 0, stream>>>(qkv, vt, mask, att);

    gemm_bf16_n64<<<dim3(16, 32), 256, 0, stream>>>(att, wpT, bproj, out, 4096, 1024, 1024);
}

// Round 7
// 168.673 us; speedup vs baseline: 1.3373x; 1.3373x over previous
//
#include <hip/hip_runtime.h>
#include <hip/hip_bf16.h>
#include <cstddef>
#include <cstdint>

#define Bb 4
#define Tt 1024
#define Dd 1024
#define Hh 16

typedef __bf16 bf16x8 __attribute__((ext_vector_type(8)));
typedef __bf16 bf16x4 __attribute__((ext_vector_type(4)));
typedef float  f32x4  __attribute__((ext_vector_type(4)));

__device__ __forceinline__ void gload16(const void* g, void* l) {
    __builtin_amdgcn_global_load_lds(
        (const __attribute__((address_space(1))) void*)g,
        (__attribute__((address_space(3))) void*)l, 16, 0, 0);
}

// ---------------------------------------------------------------------------
// Fused prep: [0,4096) cast x -> bf16; [4096,4864) Wqkv transpose;
// [4864,5120) Wproj transpose.
// ---------------------------------------------------------------------------
__global__ __launch_bounds__(256) void prep(const float* __restrict__ x,
                                            const float* __restrict__ Wqkv,
                                            const float* __restrict__ Wproj,
                                            __bf16* __restrict__ xb,
                                            __bf16* __restrict__ wqT,
                                            __bf16* __restrict__ wpT) {
    const int bid = blockIdx.x;
    if (bid < 4096) {  // cast
        int i = bid * 256 + threadIdx.x;
        float4 v = ((const float4*)x)[i];
        bf16x4 o = { (__bf16)v.x, (__bf16)v.y, (__bf16)v.z, (__bf16)v.w };
        ((bf16x4*)xb)[i] = o;
        return;
    }
    __shared__ float ld[64][65];
    const float* in;
    __bf16* out;
    int K, N, k0, n0;
    if (bid < 4096 + 768) {
        int j = bid - 4096;
        in = Wqkv; out = wqT; K = 1024; N = 3072;
        k0 = (j & 15) * 64; n0 = (j >> 4) * 64;
    } else {
        int j = bid - 4096 - 768;
        in = Wproj; out = wpT; K = 1024; N = 1024;
        k0 = (j & 15) * 64; n0 = (j >> 4) * 64;
    }
    #pragma unroll
    for (int i = 0; i < 16; i++) {
        int idx = i * 256 + threadIdx.x;
        int r = idx >> 6, c = idx & 63;
        ld[r][c] = in[(size_t)(k0 + r) * N + n0 + c];
    }
    __syncthreads();
    #pragma unroll
    for (int i = 0; i < 16; i++) {
        int idx = i * 256 + threadIdx.x;
        int r = idx >> 6, c = idx & 63;
        out[(size_t)(n0 + r) * K + k0 + c] = (__bf16)ld[c][r];
    }
}

// ---------------------------------------------------------------------------
// V slice of qkv [b][t][3072] (cols 2048 + h*64 + d) -> vt [b][h][d][t] bf16
// ---------------------------------------------------------------------------
__global__ __launch_bounds__(256) void v_transpose(const __bf16* __restrict__ qkv,
                                                   __bf16* __restrict__ vt) {
    __shared__ __bf16 ld[64][65];
    const int t0 = blockIdx.x * 64;
    const int h  = blockIdx.y;
    const int b  = blockIdx.z;
    const size_t src = ((size_t)(b * Tt + t0)) * 3072 + 2048 + h * 64;
    #pragma unroll
    for (int i = 0; i < 16; i++) {
        int idx = i * 256 + threadIdx.x;
        int tr = idx >> 6, dc = idx & 63;
        ld[tr][dc] = qkv[src + (size_t)tr * 3072 + dc];
    }
    __syncthreads();
    const size_t dst = ((size_t)((b * Hh + h) * 64)) * Tt + t0;
    #pragma unroll
    for (int i = 0; i < 16; i++) {
        int idx = i * 256 + threadIdx.x;
        int dr = idx >> 6, tc = idx & 63;
        vt[dst + (size_t)dr * Tt + tc] = ld[tc][dr];
    }
}

// ---------------------------------------------------------------------------
// 128x128 MFMA GEMM, BK=64, XOR-8 swizzled LDS. C = A @ Bt^T + bias.
// mode 0: fp32 out. mode 1 (qkv): bf16 out, cols<1024 scaled by 0.125.
// ---------------------------------------------------------------------------
__global__ __launch_bounds__(256) void gemm_bf16(const __bf16* __restrict__ A,
                                                 const __bf16* __restrict__ Bt,
                                                 const float* __restrict__ bias,
                                                 void* __restrict__ Cout,
                                                 int M, int N, int K, int mode) {
    __shared__ __align__(16) __bf16 As[128 * 64];
    __shared__ __align__(16) __bf16 Bs[128 * 64];
    const int tid  = threadIdx.x;
    const int lane = tid & 63;
    const int wave = tid >> 6;
    const int wy = wave >> 1, wx = wave & 1;
    const int l15 = lane & 15, quad = lane >> 4;
    const size_t row0 = (size_t)blockIdx.y * 128;
    const size_t col0 = (size_t)blockIdx.x * 128;

    f32x4 acc[4][4] = {};

    for (int k0 = 0; k0 < K; k0 += 64) {
        #pragma unroll
        for (int i = 0; i < 4; i++) {
            int c = i * 256 + tid;
            int r = c >> 3, seg = (c & 7) ^ (r & 7);
            gload16(&A[(row0 + r) * K + k0 + seg * 8], &As[c * 8]);
        }
        #pragma unroll
        for (int i = 0; i < 4; i++) {
            int c = i * 256 + tid;
            int r = c >> 3, seg = (c & 7) ^ (r & 7);
            gload16(&Bt[(col0 + r) * K + k0 + seg * 8], &Bs[c * 8]);
        }
        __syncthreads();
        #pragma unroll
        for (int kc = 0; kc < 2; kc++) {
            bf16x8 af[4], bfr[4];
            #pragma unroll
            for (int i = 0; i < 4; i++)
                af[i] = *(const bf16x8*)&As[(wy * 64 + i * 16 + l15) * 64 +
                                            (((kc * 4 + quad) ^ (l15 & 7)) * 8)];
            #pragma unroll
            for (int j = 0; j < 4; j++)
                bfr[j] = *(const bf16x8*)&Bs[(wx * 64 + j * 16 + l15) * 64 +
                                             (((kc * 4 + quad) ^ (l15 & 7)) * 8)];
            #pragma unroll
            for (int i = 0; i < 4; i++)
                #pragma unroll
                for (int j = 0; j < 4; j++)
                    acc[i][j] = __builtin_amdgcn_mfma_f32_16x16x32_bf16(af[i], bfr[j], acc[i][j], 0, 0, 0);
        }
        __syncthreads();
    }

    #pragma unroll
    for (int j = 0; j < 4; j++) {
        const size_t col = col0 + wx * 64 + j * 16 + l15;
        const float bj = bias[col];
        const float scale = (mode == 1 && col < 1024) ? 0.125f : 1.0f;
        #pragma unroll
        for (int i = 0; i < 4; i++) {
            const size_t row = row0 + wy * 64 + i * 16 + quad * 4;
            #pragma unroll
            for (int r = 0; r < 4; r++) {
                float v = (acc[i][j][r] + bj) * scale;
                if (mode == 1) ((__bf16*)Cout)[(row + r) * N + col] = (__bf16)v;
                else           ((float*)Cout)[(row + r) * N + col] = v;
            }
        }
    }
}

// ---------------------------------------------------------------------------
// 128x64-tile GEMM (proj), BK=64, swizzled. fp32 out.
// ---------------------------------------------------------------------------
__global__ __launch_bounds__(256) void gemm_bf16_n64(const __bf16* __restrict__ A,
                                                     const __bf16* __restrict__ Bt,
                                                     const float* __restrict__ bias,
                                                     float* __restrict__ Cout,
                                                     int M, int N, int K) {
    __shared__ __align__(16) __bf16 As[128 * 64];
    __shared__ __align__(16) __bf16 Bs[64 * 64];
    const int tid  = threadIdx.x;
    const int lane = tid & 63;
    const int wave = tid >> 6;
    const int wy = wave >> 1, wx = wave & 1;
    const int l15 = lane & 15, quad = lane >> 4;
    const size_t row0 = (size_t)blockIdx.y * 128;
    const size_t col0 = (size_t)blockIdx.x * 64;

    f32x4 acc[4][2] = {};

    for (int k0 = 0; k0 < K; k0 += 64) {
        #pragma unroll
        for (int i = 0; i < 4; i++) {
            int c = i * 256 + tid;
            int r = c >> 3, seg = (c & 7) ^ (r & 7);
            gload16(&A[(row0 + r) * K + k0 + seg * 8], &As[c * 8]);
        }
        #pragma unroll
        for (int i = 0; i < 2; i++) {
            int c = i * 256 + tid;
            int r = c >> 3, seg = (c & 7) ^ (r & 7);
            gload16(&Bt[(col0 + r) * K + k0 + seg * 8], &Bs[c * 8]);
        }
        __syncthreads();
        #pragma unroll
        for (int kc = 0; kc < 2; kc++) {
            bf16x8 af[4], bfr[2];
            #pragma unroll
            for (int i = 0; i < 4; i++)
                af[i] = *(const bf16x8*)&As[(wy * 64 + i * 16 + l15) * 64 +
                                            (((kc * 4 + quad) ^ (l15 & 7)) * 8)];
            #pragma unroll
            for (int j = 0; j < 2; j++)
                bfr[j] = *(const bf16x8*)&Bs[(wx * 32 + j * 16 + l15) * 64 +
                                             (((kc * 4 + quad) ^ (l15 & 7)) * 8)];
            #pragma unroll
            for (int i = 0; i < 4; i++)
                #pragma unroll
                for (int j = 0; j < 2; j++)
                    acc[i][j] = __builtin_amdgcn_mfma_f32_16x16x32_bf16(af[i], bfr[j], acc[i][j], 0, 0, 0);
        }
        __syncthreads();
    }

    #pragma unroll
    for (int j = 0; j < 2; j++) {
        const size_t col = col0 + wx * 32 + j * 16 + l15;
        const float bj = bias[col];
        #pragma unroll
        for (int i = 0; i < 4; i++) {
            const size_t row = row0 + wy * 64 + i * 16 + quad * 4;
            #pragma unroll
            for (int r = 0; r < 4; r++)
                Cout[(row + r) * N + col] = acc[i][j][r] + bj;
        }
    }
}

// ---------------------------------------------------------------------------
// Flash attention (S^T = K @ Q^T), R4 structure + occupancy fix:
// - LDS-DMA double-buffered K/V (zero VGPR cost), ONE __syncthreads per iter.
// - Q frags preloaded to registers; Q staged through the K buffer -> LDS
//   = 32K (K/V dbuf) + 8K (per-wave Ps) = 40 KB -> 4 blocks/CU.
// - No fold-pair; LPT dispatch instead: qt = 15 - blockIdx.y so the 16-iter
//   blocks launch first (greedy balance across 4-resident blocks/CU).
// Block = 4 waves; wave w owns q rows qt*64 + w*16 .. +16.
// ---------------------------------------------------------------------------
__global__ __launch_bounds__(256, 4) void attn_mfma(const __bf16* __restrict__ qkv,
                                                    const __bf16* __restrict__ vt,
                                                    const int* __restrict__ mask,
                                                    __bf16* __restrict__ att) {
    __shared__ __align__(16) __bf16 Ks[2][4096];
    __shared__ __align__(16) __bf16 Vs[2][4096];
    __shared__ __align__(16) __bf16 Ps[4][1024];

    const int h  = blockIdx.x & 15;
    const int b  = blockIdx.x >> 4;
    const int qt = 15 - blockIdx.y;  // LPT: longest blocks dispatch first
    const int tid = threadIdx.x, lane = tid & 63, wave = tid >> 6;
    const int l15 = lane & 15, quad = lane >> 4;

    // ---- stage Q (64x64, swizzled) through Ks[0]; preload frags; release ----
    #pragma unroll
    for (int i = 0; i < 2; i++) {
        int c = i * 256 + tid;
        int rr = c >> 3, ch = c & 7;
        gload16(&qkv[((size_t)(b * Tt + qt * 64 + rr)) * 3072 + h * 64 + ((ch ^ (rr & 7)) * 8)],
                &Ks[0][c * 8]);
    }
    __syncthreads();
    bf16x8 qf0 = *(const bf16x8*)&Ks[0][(wave * 16 + l15) * 64 + ((quad ^ (l15 & 7)) * 8)];
    bf16x8 qf1 = *(const bf16x8*)&Ks[0][(wave * 16 + l15) * 64 + (((4 + quad) ^ (l15 & 7)) * 8)];
    __syncthreads();  // Q frag reads done -> Ks[0] reusable

    // ---- stage K/V for kt=0 into buf 0 ----
    #pragma unroll
    for (int i = 0; i < 2; i++) {
        int c = i * 256 + tid;
        int rr = c >> 3, ch = c & 7, sw = ((ch ^ (rr & 7)) * 8);
        gload16(&qkv[((size_t)(b * Tt + rr)) * 3072 + 1024 + h * 64 + sw], &Ks[0][c * 8]);
        gload16(&vt[((size_t)((b * Hh + h) * 64 + rr)) * Tt + sw], &Vs[0][c * 8]);
    }

    f32x4 Oacc[4] = {};
    float lsum = 0.0f;

    for (int kt = 0; kt <= qt; kt++) {
        __syncthreads();  // DMA(kt) complete; all waves done reading buf^1
        const int cur = kt & 1;
        if (kt < qt) {  // prefetch next K/V into buf^1 (full compute phase of slack)
            #pragma unroll
            for (int i = 0; i < 2; i++) {
                int c = i * 256 + tid;
                int rr = c >> 3, ch = c & 7, sw = ((ch ^ (rr & 7)) * 8);
                gload16(&qkv[((size_t)(b * Tt + (kt + 1) * 64 + rr)) * 3072 + 1024 + h * 64 + sw],
                        &Ks[cur ^ 1][c * 8]);
                gload16(&vt[((size_t)((b * Hh + h) * 64 + rr)) * Tt + (kt + 1) * 64 + sw],
                        &Vs[cur ^ 1][c * 8]);
            }
        }

        int mv4[4][4];
        #pragma unroll
        for (int j = 0; j < 4; j++) {
            const int4 m4 = *(const int4*)&mask[b * Tt + kt * 64 + j * 16 + quad * 4];
            mv4[j][0] = m4.x; mv4[j][1] = m4.y; mv4[j][2] = m4.z; mv4[j][3] = m4.w;
        }

        // K fragments, then S^T + exp + P (per-wave LDS strip, lgkmcnt-ordered)
        bf16x8 ak[4][2];
        #pragma unroll
        for (int j = 0; j < 4; j++)
            #pragma unroll
            for (int kc = 0; kc < 2; kc++)
                ak[j][kc] = *(const bf16x8*)&Ks[cur][(j * 16 + l15) * 64 +
                                                     (((kc * 4 + quad) ^ (l15 & 7)) * 8)];
        #pragma unroll
        for (int j = 0; j < 4; j++) {
            f32x4 st = {};
            st = __builtin_amdgcn_mfma_f32_16x16x32_bf16(ak[j][0], qf0, st, 0, 0, 0);
            st = __builtin_amdgcn_mfma_f32_16x16x32_bf16(ak[j][1], qf1, st, 0, 0, 0);
            bf16x4 pv;
            #pragma unroll
            for (int r = 0; r < 4; r++) {
                const int tloc = j * 16 + quad * 4 + r;
                bool keep = (mv4[j][r] != 0);
                if (kt == qt) keep = keep && (tloc <= wave * 16 + l15);
                const float pe = keep ? __expf(st[r]) : 0.0f;
                lsum += pe;
                pv[r] = (__bf16)pe;
            }
            *(bf16x4*)&Ps[wave][l15 * 64 + (((j * 4 + quad) ^ ((l15 & 7) << 1)) * 4)] = pv;
        }

        // V fragments + PV
        bf16x8 av[4][2];
        #pragma unroll
        for (int n = 0; n < 4; n++)
            #pragma unroll
            for (int kc = 0; kc < 2; kc++)
                av[n][kc] = *(const bf16x8*)&Vs[cur][(n * 16 + l15) * 64 +
                                                     (((kc * 4 + quad) ^ (l15 & 7)) * 8)];
        bf16x8 p0 = *(const bf16x8*)&Ps[wave][l15 * 64 + (((2 * quad) ^ ((l15 & 7) << 1)) * 4)];
        bf16x8 p1 = *(const bf16x8*)&Ps[wave][l15 * 64 + (((2 * (4 + quad)) ^ ((l15 & 7) << 1)) * 4)];
        #pragma unroll
        for (int n = 0; n < 4; n++) {
            Oacc[n] = __builtin_amdgcn_mfma_f32_16x16x32_bf16(av[n][0], p0, Oacc[n], 0, 0, 0);
            Oacc[n] = __builtin_amdgcn_mfma_f32_16x16x32_bf16(av[n][1], p1, Oacc[n], 0, 0, 0);
        }
    }

    // epilogue: reduce l across quads, normalize, store (O^T: lane col = q)
    float lt = lsum;
    lt += __shfl_xor(lt, 16);
    lt += __shfl_xor(lt, 32);
    const float inv = 1.0f / lt;
    const int q = qt * 64 + wave * 16 + l15;
    #pragma unroll
    for (int n = 0; n < 4; n++) {
        bf16x4 o;
        #pragma unroll
        for (int r = 0; r < 4; r++) o[r] = (__bf16)(Oacc[n][r] * inv);
        *(bf16x4*)&att[((size_t)(b * Tt + q)) * Dd + h * 64 + n * 16 + quad * 4] = o;
    }
}

// ---------------------------------------------------------------------------
extern "C" void kernel_launch(void* const* d_in, const int* in_sizes, int n_in,
                              void* d_out, int out_size, void* d_ws, size_t ws_size,
                              hipStream_t stream) {
    const float* x     = (const float*)d_in[0];
    const float* Wqkv  = (const float*)d_in[1];
    const float* bqkv  = (const float*)d_in[2];
    const float* Wproj = (const float*)d_in[3];
    const float* bproj = (const float*)d_in[4];
    const int*   mask  = (const int*)d_in[5];
    float* out = (float*)d_out;

    __bf16* xb  = (__bf16*)d_ws;                         // 4096*1024
    __bf16* wqT = xb  + (size_t)4096 * 1024;             // 3072*1024
    __bf16* wpT = wqT + (size_t)3072 * 1024;             // 1024*1024
    __bf16* qkv = wpT + (size_t)1024 * 1024;             // 4096*3072
    __bf16* vt  = qkv + (size_t)4096 * 3072;             // 4*16*64*1024
    __bf16* att = vt  + (size_t)4 * 16 * 64 * 1024;      // 4096*1024

    prep<<<4096 + 768 + 256, 256, 0, stream>>>(x, Wqkv, Wproj, xb, wqT, wpT);

    gemm_bf16<<<dim3(24, 32), 256, 0, stream>>>(xb, wqT, bqkv, qkv, 4096, 3072, 1024, 1);

    v_transpose<<<dim3(16, 16, 4), 256, 0, stream>>>(qkv, vt);
    attn_mfma<<<dim3(64, 16), 256, 0, stream>>>(qkv, vt, mask, att);

    gemm_bf16_n64<<<dim3(16, 32), 256, 0, stream>>>(att, wpT, bproj, out, 4096, 1024, 1024);
}

// Round 8
// 166.384 us; speedup vs baseline: 1.3557x; 1.0138x over previous
//
#include <hip/hip_runtime.h>
#include <hip/hip_bf16.h>
#include <cstddef>
#include <cstdint>

#define Bb 4
#define Tt 1024
#define Dd 1024
#define Hh 16

typedef __bf16 bf16x8 __attribute__((ext_vector_type(8)));
typedef __bf16 bf16x4 __attribute__((ext_vector_type(4)));
typedef float  f32x4  __attribute__((ext_vector_type(4)));

__device__ __forceinline__ void gload16(const void* g, void* l) {
    __builtin_amdgcn_global_load_lds(
        (const __attribute__((address_space(1))) void*)g,
        (__attribute__((address_space(3))) void*)l, 16, 0, 0);
}

// ---------------------------------------------------------------------------
// Fused prep: [0,4096) cast x -> bf16; [4096,4864) Wqkv transpose;
// [4864,5120) Wproj transpose.
// ---------------------------------------------------------------------------
__global__ __launch_bounds__(256) void prep(const float* __restrict__ x,
                                            const float* __restrict__ Wqkv,
                                            const float* __restrict__ Wproj,
                                            __bf16* __restrict__ xb,
                                            __bf16* __restrict__ wqT,
                                            __bf16* __restrict__ wpT) {
    const int bid = blockIdx.x;
    if (bid < 4096) {  // cast
        int i = bid * 256 + threadIdx.x;
        float4 v = ((const float4*)x)[i];
        bf16x4 o = { (__bf16)v.x, (__bf16)v.y, (__bf16)v.z, (__bf16)v.w };
        ((bf16x4*)xb)[i] = o;
        return;
    }
    __shared__ float ld[64][65];
    const float* in;
    __bf16* out;
    int K, N, k0, n0;
    if (bid < 4096 + 768) {
        int j = bid - 4096;
        in = Wqkv; out = wqT; K = 1024; N = 3072;
        k0 = (j & 15) * 64; n0 = (j >> 4) * 64;
    } else {
        int j = bid - 4096 - 768;
        in = Wproj; out = wpT; K = 1024; N = 1024;
        k0 = (j & 15) * 64; n0 = (j >> 4) * 64;
    }
    #pragma unroll
    for (int i = 0; i < 16; i++) {
        int idx = i * 256 + threadIdx.x;
        int r = idx >> 6, c = idx & 63;
        ld[r][c] = in[(size_t)(k0 + r) * N + n0 + c];
    }
    __syncthreads();
    #pragma unroll
    for (int i = 0; i < 16; i++) {
        int idx = i * 256 + threadIdx.x;
        int r = idx >> 6, c = idx & 63;
        out[(size_t)(n0 + r) * K + k0 + c] = (__bf16)ld[c][r];
    }
}

// ---------------------------------------------------------------------------
// V slice of qkv [b][t][3072] (cols 2048 + h*64 + d) -> vt [b][h][d][t] bf16
// ---------------------------------------------------------------------------
__global__ __launch_bounds__(256) void v_transpose(const __bf16* __restrict__ qkv,
                                                   __bf16* __restrict__ vt) {
    __shared__ __bf16 ld[64][65];
    const int t0 = blockIdx.x * 64;
    const int h  = blockIdx.y;
    const int b  = blockIdx.z;
    const size_t src = ((size_t)(b * Tt + t0)) * 3072 + 2048 + h * 64;
    #pragma unroll
    for (int i = 0; i < 16; i++) {
        int idx = i * 256 + threadIdx.x;
        int tr = idx >> 6, dc = idx & 63;
        ld[tr][dc] = qkv[src + (size_t)tr * 3072 + dc];
    }
    __syncthreads();
    const size_t dst = ((size_t)((b * Hh + h) * 64)) * Tt + t0;
    #pragma unroll
    for (int i = 0; i < 16; i++) {
        int idx = i * 256 + threadIdx.x;
        int dr = idx >> 6, tc = idx & 63;
        vt[dst + (size_t)dr * Tt + tc] = ld[tc][dr];
    }
}

// ---------------------------------------------------------------------------
// 128x128 MFMA GEMM, BK=32, DOUBLE-BUFFERED LDS with one barrier per iter:
// prefetch DMA issued after the barrier -> full compute phase of slack.
// Epilogue: acc -> padded LDS tile -> coalesced 16B/lane stores.
// mode 1 (qkv): bf16 out, cols<1024 scaled by 0.125.
// ---------------------------------------------------------------------------
__global__ __launch_bounds__(256) void gemm_bf16(const __bf16* __restrict__ A,
                                                 const __bf16* __restrict__ Bt,
                                                 const float* __restrict__ bias,
                                                 __bf16* __restrict__ Cout,
                                                 int M, int N, int K) {
    // K-loop: As 2x4096, Bs 2x4096 (32 KB). Epilogue: bf16 tile 128x132 (33.8 KB).
    __shared__ __align__(16) __bf16 smem[17408];  // 34816 B
    __bf16* const As = smem;          // [2][4096]
    __bf16* const Bs = smem + 8192;   // [2][4096]

    const int tid  = threadIdx.x;
    const int lane = tid & 63;
    const int wave = tid >> 6;
    const int wy = wave >> 1, wx = wave & 1;
    const int l15 = lane & 15, quad = lane >> 4;
    const size_t row0 = (size_t)blockIdx.y * 128;
    const size_t col0 = (size_t)blockIdx.x * 128;

    f32x4 acc[4][4] = {};

    // prologue: stage k0=0 into buf 0. chunk c: row r=c>>2, pos=c&3,
    // src seg = pos ^ ((r>>1)&3)  (conflict-free frag reads, <=2-way)
    #pragma unroll
    for (int i = 0; i < 2; i++) {
        int c = i * 256 + tid;
        int r = c >> 2, seg = (c & 3) ^ ((r >> 1) & 3);
        gload16(&A[(row0 + r) * K + seg * 8], &As[c * 8]);
        gload16(&Bt[(col0 + r) * K + seg * 8], &Bs[c * 8]);
    }

    const int niter = K >> 5;  // 32
    for (int it = 0; it < niter; it++) {
        __syncthreads();  // buf[cur] DMA done; buf[cur^1] frag reads done
        const int cur = it & 1;
        if (it + 1 < niter) {  // prefetch next k-slice into buf^1
            const int k0 = (it + 1) << 5;
            #pragma unroll
            for (int i = 0; i < 2; i++) {
                int c = i * 256 + tid;
                int r = c >> 2, seg = (c & 3) ^ ((r >> 1) & 3);
                gload16(&A[(row0 + r) * K + k0 + seg * 8], &As[(cur ^ 1) * 4096 + c * 8]);
                gload16(&Bt[(col0 + r) * K + k0 + seg * 8], &Bs[(cur ^ 1) * 4096 + c * 8]);
            }
        }
        bf16x8 af[4], bfr[4];
        #pragma unroll
        for (int i = 0; i < 4; i++) {
            const int r = wy * 64 + i * 16 + l15;
            af[i] = *(const bf16x8*)&As[cur * 4096 + r * 32 + ((quad ^ ((r >> 1) & 3)) * 8)];
        }
        #pragma unroll
        for (int j = 0; j < 4; j++) {
            const int r = wx * 64 + j * 16 + l15;
            bfr[j] = *(const bf16x8*)&Bs[cur * 4096 + r * 32 + ((quad ^ ((r >> 1) & 3)) * 8)];
        }
        #pragma unroll
        for (int i = 0; i < 4; i++)
            #pragma unroll
            for (int j = 0; j < 4; j++)
                acc[i][j] = __builtin_amdgcn_mfma_f32_16x16x32_bf16(af[i], bfr[j], acc[i][j], 0, 0, 0);
    }

    // ---- epilogue: bias+scale -> LDS tile (stride 132) -> coalesced stores ----
    __syncthreads();  // K-loop LDS dead
    #pragma unroll
    for (int j = 0; j < 4; j++) {
        const int cl = wx * 64 + j * 16 + l15;
        const size_t col = col0 + cl;
        const float bj = bias[col];
        const float scale = (col < 1024) ? 0.125f : 1.0f;
        #pragma unroll
        for (int i = 0; i < 4; i++) {
            const int rl = wy * 64 + i * 16 + quad * 4;
            #pragma unroll
            for (int r = 0; r < 4; r++)
                smem[(rl + r) * 132 + cl] = (__bf16)((acc[i][j][r] + bj) * scale);
        }
    }
    __syncthreads();
    #pragma unroll
    for (int p = 0; p < 8; p++) {
        const int row = p * 16 + (tid >> 4);
        const int ch  = tid & 15;
        bf16x8 v = *(const bf16x8*)&smem[row * 132 + ch * 8];
        *(bf16x8*)&Cout[(row0 + row) * N + col0 + ch * 8] = v;
    }
}

// ---------------------------------------------------------------------------
// 128x64-tile GEMM (proj), BK=32, double-buffered, fp32 out via LDS epilogue.
// ---------------------------------------------------------------------------
__global__ __launch_bounds__(256) void gemm_bf16_n64(const __bf16* __restrict__ A,
                                                     const __bf16* __restrict__ Bt,
                                                     const float* __restrict__ bias,
                                                     float* __restrict__ Cout,
                                                     int M, int N, int K) {
    // K-loop: As 2x4096, Bs 2x2048 (24 KB). Epilogue: f32 tile 128x66 (33.8 KB).
    __shared__ __align__(16) __bf16 smem[17408];  // 34816 B
    __bf16* const As = smem;          // [2][4096]
    __bf16* const Bs = smem + 8192;   // [2][2048]
    float* const Ct = (float*)smem;   // epilogue view

    const int tid  = threadIdx.x;
    const int lane = tid & 63;
    const int wave = tid >> 6;
    const int wy = wave >> 1, wx = wave & 1;
    const int l15 = lane & 15, quad = lane >> 4;
    const size_t row0 = (size_t)blockIdx.y * 128;
    const size_t col0 = (size_t)blockIdx.x * 64;

    f32x4 acc[4][2] = {};

    #pragma unroll
    for (int i = 0; i < 2; i++) {
        int c = i * 256 + tid;
        int r = c >> 2, seg = (c & 3) ^ ((r >> 1) & 3);
        gload16(&A[(row0 + r) * K + seg * 8], &As[c * 8]);
    }
    {
        int c = tid;
        int r = c >> 2, seg = (c & 3) ^ ((r >> 1) & 3);
        gload16(&Bt[(col0 + r) * K + seg * 8], &Bs[c * 8]);
    }

    const int niter = K >> 5;
    for (int it = 0; it < niter; it++) {
        __syncthreads();
        const int cur = it & 1;
        if (it + 1 < niter) {
            const int k0 = (it + 1) << 5;
            #pragma unroll
            for (int i = 0; i < 2; i++) {
                int c = i * 256 + tid;
                int r = c >> 2, seg = (c & 3) ^ ((r >> 1) & 3);
                gload16(&A[(row0 + r) * K + k0 + seg * 8], &As[(cur ^ 1) * 4096 + c * 8]);
            }
            {
                int c = tid;
                int r = c >> 2, seg = (c & 3) ^ ((r >> 1) & 3);
                gload16(&Bt[(col0 + r) * K + k0 + seg * 8], &Bs[(cur ^ 1) * 2048 + c * 8]);
            }
        }
        bf16x8 af[4], bfr[2];
        #pragma unroll
        for (int i = 0; i < 4; i++) {
            const int r = wy * 64 + i * 16 + l15;
            af[i] = *(const bf16x8*)&As[cur * 4096 + r * 32 + ((quad ^ ((r >> 1) & 3)) * 8)];
        }
        #pragma unroll
        for (int j = 0; j < 2; j++) {
            const int r = wx * 32 + j * 16 + l15;
            bfr[j] = *(const bf16x8*)&Bs[cur * 2048 + r * 32 + ((quad ^ ((r >> 1) & 3)) * 8)];
        }
        #pragma unroll
        for (int i = 0; i < 4; i++)
            #pragma unroll
            for (int j = 0; j < 2; j++)
                acc[i][j] = __builtin_amdgcn_mfma_f32_16x16x32_bf16(af[i], bfr[j], acc[i][j], 0, 0, 0);
    }

    // ---- epilogue: bias -> f32 LDS tile (stride 66) -> coalesced float4 stores ----
    __syncthreads();
    #pragma unroll
    for (int j = 0; j < 2; j++) {
        const int cl = wx * 32 + j * 16 + l15;
        const float bj = bias[col0 + cl];
        #pragma unroll
        for (int i = 0; i < 4; i++) {
            const int rl = wy * 64 + i * 16 + quad * 4;
            #pragma unroll
            for (int r = 0; r < 4; r++)
                Ct[(rl + r) * 66 + cl] = acc[i][j][r] + bj;
        }
    }
    __syncthreads();
    #pragma unroll
    for (int p = 0; p < 8; p++) {
        const int row = p * 16 + (tid >> 4);
        const int ch  = tid & 15;
        f32x4 v = *(const f32x4*)&Ct[row * 66 + ch * 4];
        *(f32x4*)&Cout[(row0 + row) * N + col0 + ch * 4] = v;
    }
}

// ---------------------------------------------------------------------------
// Flash attention (S^T = K @ Q^T) — unchanged from R7 (validated):
// dbuf K/V via LDS-DMA, one barrier/iter, prefetch with full-phase slack,
// Q frags in registers, per-wave Ps strip, LPT dispatch. 40 KB, 4 blocks/CU.
// ---------------------------------------------------------------------------
__global__ __launch_bounds__(256, 4) void attn_mfma(const __bf16* __restrict__ qkv,
                                                    const __bf16* __restrict__ vt,
                                                    const int* __restrict__ mask,
                                                    __bf16* __restrict__ att) {
    __shared__ __align__(16) __bf16 Ks[2][4096];
    __shared__ __align__(16) __bf16 Vs[2][4096];
    __shared__ __align__(16) __bf16 Ps[4][1024];

    const int h  = blockIdx.x & 15;
    const int b  = blockIdx.x >> 4;
    const int qt = 15 - blockIdx.y;  // LPT: longest blocks dispatch first
    const int tid = threadIdx.x, lane = tid & 63, wave = tid >> 6;
    const int l15 = lane & 15, quad = lane >> 4;

    #pragma unroll
    for (int i = 0; i < 2; i++) {
        int c = i * 256 + tid;
        int rr = c >> 3, ch = c & 7;
        gload16(&qkv[((size_t)(b * Tt + qt * 64 + rr)) * 3072 + h * 64 + ((ch ^ (rr & 7)) * 8)],
                &Ks[0][c * 8]);
    }
    __syncthreads();
    bf16x8 qf0 = *(const bf16x8*)&Ks[0][(wave * 16 + l15) * 64 + ((quad ^ (l15 & 7)) * 8)];
    bf16x8 qf1 = *(const bf16x8*)&Ks[0][(wave * 16 + l15) * 64 + (((4 + quad) ^ (l15 & 7)) * 8)];
    __syncthreads();

    #pragma unroll
    for (int i = 0; i < 2; i++) {
        int c = i * 256 + tid;
        int rr = c >> 3, ch = c & 7, sw = ((ch ^ (rr & 7)) * 8);
        gload16(&qkv[((size_t)(b * Tt + rr)) * 3072 + 1024 + h * 64 + sw], &Ks[0][c * 8]);
        gload16(&vt[((size_t)((b * Hh + h) * 64 + rr)) * Tt + sw], &Vs[0][c * 8]);
    }

    f32x4 Oacc[4] = {};
    float lsum = 0.0f;

    for (int kt = 0; kt <= qt; kt++) {
        __syncthreads();
        const int cur = kt & 1;
        if (kt < qt) {
            #pragma unroll
            for (int i = 0; i < 2; i++) {
                int c = i * 256 + tid;
                int rr = c >> 3, ch = c & 7, sw = ((ch ^ (rr & 7)) * 8);
                gload16(&qkv[((size_t)(b * Tt + (kt + 1) * 64 + rr)) * 3072 + 1024 + h * 64 + sw],
                        &Ks[cur ^ 1][c * 8]);
                gload16(&vt[((size_t)((b * Hh + h) * 64 + rr)) * Tt + (kt + 1) * 64 + sw],
                        &Vs[cur ^ 1][c * 8]);
            }
        }

        int mv4[4][4];
        #pragma unroll
        for (int j = 0; j < 4; j++) {
            const int4 m4 = *(const int4*)&mask[b * Tt + kt * 64 + j * 16 + quad * 4];
            mv4[j][0] = m4.x; mv4[j][1] = m4.y; mv4[j][2] = m4.z; mv4[j][3] = m4.w;
        }

        bf16x8 ak[4][2];
        #pragma unroll
        for (int j = 0; j < 4; j++)
            #pragma unroll
            for (int kc = 0; kc < 2; kc++)
                ak[j][kc] = *(const bf16x8*)&Ks[cur][(j * 16 + l15) * 64 +
                                                     (((kc * 4 + quad) ^ (l15 & 7)) * 8)];
        #pragma unroll
        for (int j = 0; j < 4; j++) {
            f32x4 st = {};
            st = __builtin_amdgcn_mfma_f32_16x16x32_bf16(ak[j][0], qf0, st, 0, 0, 0);
            st = __builtin_amdgcn_mfma_f32_16x16x32_bf16(ak[j][1], qf1, st, 0, 0, 0);
            bf16x4 pv;
            #pragma unroll
            for (int r = 0; r < 4; r++) {
                const int tloc = j * 16 + quad * 4 + r;
                bool keep = (mv4[j][r] != 0);
                if (kt == qt) keep = keep && (tloc <= wave * 16 + l15);
                const float pe = keep ? __expf(st[r]) : 0.0f;
                lsum += pe;
                pv[r] = (__bf16)pe;
            }
            *(bf16x4*)&Ps[wave][l15 * 64 + (((j * 4 + quad) ^ ((l15 & 7) << 1)) * 4)] = pv;
        }

        bf16x8 av[4][2];
        #pragma unroll
        for (int n = 0; n < 4; n++)
            #pragma unroll
            for (int kc = 0; kc < 2; kc++)
                av[n][kc] = *(const bf16x8*)&Vs[cur][(n * 16 + l15) * 64 +
                                                     (((kc * 4 + quad) ^ (l15 & 7)) * 8)];
        bf16x8 p0 = *(const bf16x8*)&Ps[wave][l15 * 64 + (((2 * quad) ^ ((l15 & 7) << 1)) * 4)];
        bf16x8 p1 = *(const bf16x8*)&Ps[wave][l15 * 64 + (((2 * (4 + quad)) ^ ((l15 & 7) << 1)) * 4)];
        #pragma unroll
        for (int n = 0; n < 4; n++) {
            Oacc[n] = __builtin_amdgcn_mfma_f32_16x16x32_bf16(av[n][0], p0, Oacc[n], 0, 0, 0);
            Oacc[n] = __builtin_amdgcn_mfma_f32_16x16x32_bf16(av[n][1], p1, Oacc[n], 0, 0, 0);
        }
    }

    float lt = lsum;
    lt += __shfl_xor(lt, 16);
    lt += __shfl_xor(lt, 32);
    const float inv = 1.0f / lt;
    const int q = qt * 64 + wave * 16 + l15;
    #pragma unroll
    for (int n = 0; n < 4; n++) {
        bf16x4 o;
        #pragma unroll
        for (int r = 0; r < 4; r++) o[r] = (__bf16)(Oacc[n][r] * inv);
        *(bf16x4*)&att[((size_t)(b * Tt + q)) * Dd + h * 64 + n * 16 + quad * 4] = o;
    }
}

// ---------------------------------------------------------------------------
extern "C" void kernel_launch(void* const* d_in, const int* in_sizes, int n_in,
                              void* d_out, int out_size, void* d_ws, size_t ws_size,
                              hipStream_t stream) {
    const float* x     = (const float*)d_in[0];
    const float* Wqkv  = (const float*)d_in[1];
    const float* bqkv  = (const float*)d_in[2];
    const float* Wproj = (const float*)d_in[3];
    const float* bproj = (const float*)d_in[4];
    const int*   mask  = (const int*)d_in[5];
    float* out = (float*)d_out;

    __bf16* xb  = (__bf16*)d_ws;                         // 4096*1024
    __bf16* wqT = xb  + (size_t)4096 * 1024;             // 3072*1024
    __bf16* wpT = wqT + (size_t)3072 * 1024;             // 1024*1024
    __bf16* qkv = wpT + (size_t)1024 * 1024;             // 4096*3072
    __bf16* vt  = qkv + (size_t)4096 * 3072;             // 4*16*64*1024
    __bf16* att = vt  + (size_t)4 * 16 * 64 * 1024;      // 4096*1024

    prep<<<4096 + 768 + 256, 256, 0, stream>>>(x, Wqkv, Wproj, xb, wqT, wpT);

    gemm_bf16<<<dim3(24, 32), 256, 0, stream>>>(xb, wqT, bqkv, qkv, 4096, 3072, 1024);

    v_transpose<<<dim3(16, 16, 4), 256, 0, stream>>>(qkv, vt);
    attn_mfma<<<dim3(64, 16), 256, 0, stream>>>(qkv, vt, mask, att);

    gemm_bf16_n64<<<dim3(16, 32), 256, 0, stream>>>(att, wpT, bproj, out, 4096, 1024, 1024);
}

// Round 9
// 163.115 us; speedup vs baseline: 1.3829x; 1.0200x over previous
//
#include <hip/hip_runtime.h>
#include <hip/hip_bf16.h>
#include <cstddef>
#include <cstdint>

#define Bb 4
#define Tt 1024
#define Dd 1024
#define Hh 16

typedef __bf16 bf16x8 __attribute__((ext_vector_type(8)));
typedef __bf16 bf16x4 __attribute__((ext_vector_type(4)));
typedef float  f32x4  __attribute__((ext_vector_type(4)));

__device__ __forceinline__ void gload16(const void* g, void* l) {
    __builtin_amdgcn_global_load_lds(
        (const __attribute__((address_space(1))) void*)g,
        (__attribute__((address_space(3))) void*)l, 16, 0, 0);
}

// ---------------------------------------------------------------------------
// Fused prep: [0,4096) cast x -> bf16; [4096,4864) Wqkv transpose;
// [4864,5120) Wproj transpose.
// ---------------------------------------------------------------------------
__global__ __launch_bounds__(256) void prep(const float* __restrict__ x,
                                            const float* __restrict__ Wqkv,
                                            const float* __restrict__ Wproj,
                                            __bf16* __restrict__ xb,
                                            __bf16* __restrict__ wqT,
                                            __bf16* __restrict__ wpT) {
    const int bid = blockIdx.x;
    if (bid < 4096) {  // cast
        int i = bid * 256 + threadIdx.x;
        float4 v = ((const float4*)x)[i];
        bf16x4 o = { (__bf16)v.x, (__bf16)v.y, (__bf16)v.z, (__bf16)v.w };
        ((bf16x4*)xb)[i] = o;
        return;
    }
    __shared__ float ld[64][65];
    const float* in;
    __bf16* out;
    int K, N, k0, n0;
    if (bid < 4096 + 768) {
        int j = bid - 4096;
        in = Wqkv; out = wqT; K = 1024; N = 3072;
        k0 = (j & 15) * 64; n0 = (j >> 4) * 64;
    } else {
        int j = bid - 4096 - 768;
        in = Wproj; out = wpT; K = 1024; N = 1024;
        k0 = (j & 15) * 64; n0 = (j >> 4) * 64;
    }
    #pragma unroll
    for (int i = 0; i < 16; i++) {
        int idx = i * 256 + threadIdx.x;
        int r = idx >> 6, c = idx & 63;
        ld[r][c] = in[(size_t)(k0 + r) * N + n0 + c];
    }
    __syncthreads();
    #pragma unroll
    for (int i = 0; i < 16; i++) {
        int idx = i * 256 + threadIdx.x;
        int r = idx >> 6, c = idx & 63;
        out[(size_t)(n0 + r) * K + k0 + c] = (__bf16)ld[c][r];
    }
}

// ---------------------------------------------------------------------------
// 128x128 MFMA GEMM (QKV), BK=32, double-buffered, one barrier/iter.
// Epilogue: acc -> padded LDS tile -> coalesced bf16x8 stores; for V columns
// (col0 >= 2048) ALSO emits the transposed vt[b][h][d][t] copy from the same
// LDS tile (kills the standalone v_transpose kernel).
// Q columns (<1024) pre-scaled by 0.125.
// ---------------------------------------------------------------------------
__global__ __launch_bounds__(256) void gemm_qkv(const __bf16* __restrict__ A,
                                                const __bf16* __restrict__ Bt,
                                                const float* __restrict__ bias,
                                                __bf16* __restrict__ Cout,
                                                __bf16* __restrict__ vt,
                                                int M, int N, int K) {
    __shared__ __align__(16) __bf16 smem[17408];  // 34816 B
    __bf16* const As = smem;          // [2][4096]
    __bf16* const Bs = smem + 8192;   // [2][4096]

    const int tid  = threadIdx.x;
    const int lane = tid & 63;
    const int wave = tid >> 6;
    const int wy = wave >> 1, wx = wave & 1;
    const int l15 = lane & 15, quad = lane >> 4;
    const size_t row0 = (size_t)blockIdx.y * 128;
    const size_t col0 = (size_t)blockIdx.x * 128;

    f32x4 acc[4][4] = {};

    #pragma unroll
    for (int i = 0; i < 2; i++) {
        int c = i * 256 + tid;
        int r = c >> 2, seg = (c & 3) ^ ((r >> 1) & 3);
        gload16(&A[(row0 + r) * K + seg * 8], &As[c * 8]);
        gload16(&Bt[(col0 + r) * K + seg * 8], &Bs[c * 8]);
    }

    const int niter = K >> 5;  // 32
    for (int it = 0; it < niter; it++) {
        __syncthreads();
        const int cur = it & 1;
        if (it + 1 < niter) {
            const int k0 = (it + 1) << 5;
            #pragma unroll
            for (int i = 0; i < 2; i++) {
                int c = i * 256 + tid;
                int r = c >> 2, seg = (c & 3) ^ ((r >> 1) & 3);
                gload16(&A[(row0 + r) * K + k0 + seg * 8], &As[(cur ^ 1) * 4096 + c * 8]);
                gload16(&Bt[(col0 + r) * K + k0 + seg * 8], &Bs[(cur ^ 1) * 4096 + c * 8]);
            }
        }
        bf16x8 af[4], bfr[4];
        #pragma unroll
        for (int i = 0; i < 4; i++) {
            const int r = wy * 64 + i * 16 + l15;
            af[i] = *(const bf16x8*)&As[cur * 4096 + r * 32 + ((quad ^ ((r >> 1) & 3)) * 8)];
        }
        #pragma unroll
        for (int j = 0; j < 4; j++) {
            const int r = wx * 64 + j * 16 + l15;
            bfr[j] = *(const bf16x8*)&Bs[cur * 4096 + r * 32 + ((quad ^ ((r >> 1) & 3)) * 8)];
        }
        #pragma unroll
        for (int i = 0; i < 4; i++)
            #pragma unroll
            for (int j = 0; j < 4; j++)
                acc[i][j] = __builtin_amdgcn_mfma_f32_16x16x32_bf16(af[i], bfr[j], acc[i][j], 0, 0, 0);
    }

    // ---- epilogue: bias+scale -> LDS tile (stride 132) -> coalesced stores ----
    __syncthreads();
    #pragma unroll
    for (int j = 0; j < 4; j++) {
        const int cl = wx * 64 + j * 16 + l15;
        const size_t col = col0 + cl;
        const float bj = bias[col];
        const float scale = (col < 1024) ? 0.125f : 1.0f;
        #pragma unroll
        for (int i = 0; i < 4; i++) {
            const int rl = wy * 64 + i * 16 + quad * 4;
            #pragma unroll
            for (int r = 0; r < 4; r++)
                smem[(rl + r) * 132 + cl] = (__bf16)((acc[i][j][r] + bj) * scale);
        }
    }
    __syncthreads();
    #pragma unroll
    for (int p = 0; p < 8; p++) {
        const int row = p * 16 + (tid >> 4);
        const int ch  = tid & 15;
        bf16x8 v = *(const bf16x8*)&smem[row * 132 + ch * 8];
        *(bf16x8*)&Cout[(row0 + row) * N + col0 + ch * 8] = v;
    }
    if (col0 >= 2048) {  // V block: also write vt[b][h][d][t] (t = M rows)
        const int bidx = (int)(row0 >> 10);
        const int t0g  = (int)(row0 & 1023);
        const int cl   = tid >> 1;          // tile column 0..127
        const int half = tid & 1;           // t-half 0..1
        const int hd   = (int)(col0 - 2048) + cl;
        const size_t vrow = ((size_t)((bidx * Hh + (hd >> 6)) * 64 + (hd & 63))) * Tt + t0g;
        #pragma unroll
        for (int s = 0; s < 8; s++) {
            const int t = half * 64 + s * 8;
            bf16x8 v;
            #pragma unroll
            for (int u = 0; u < 8; u++) v[u] = smem[(t + u) * 132 + cl];
            *(bf16x8*)&vt[vrow + t] = v;
        }
    }
}

// ---------------------------------------------------------------------------
// 128x64-tile GEMM (proj), BK=64, single-buffered (R7 form — its 64-MFMA
// compute phase per barrier covers the DMA latency; BK=32 dbuf regressed).
// ---------------------------------------------------------------------------
__global__ __launch_bounds__(256) void gemm_bf16_n64(const __bf16* __restrict__ A,
                                                     const __bf16* __restrict__ Bt,
                                                     const float* __restrict__ bias,
                                                     float* __restrict__ Cout,
                                                     int M, int N, int K) {
    __shared__ __align__(16) __bf16 As[128 * 64];
    __shared__ __align__(16) __bf16 Bs[64 * 64];
    const int tid  = threadIdx.x;
    const int lane = tid & 63;
    const int wave = tid >> 6;
    const int wy = wave >> 1, wx = wave & 1;
    const int l15 = lane & 15, quad = lane >> 4;
    const size_t row0 = (size_t)blockIdx.y * 128;
    const size_t col0 = (size_t)blockIdx.x * 64;

    f32x4 acc[4][2] = {};

    for (int k0 = 0; k0 < K; k0 += 64) {
        #pragma unroll
        for (int i = 0; i < 4; i++) {
            int c = i * 256 + tid;
            int r = c >> 3, seg = (c & 7) ^ (r & 7);
            gload16(&A[(row0 + r) * K + k0 + seg * 8], &As[c * 8]);
        }
        #pragma unroll
        for (int i = 0; i < 2; i++) {
            int c = i * 256 + tid;
            int r = c >> 3, seg = (c & 7) ^ (r & 7);
            gload16(&Bt[(col0 + r) * K + k0 + seg * 8], &Bs[c * 8]);
        }
        __syncthreads();
        #pragma unroll
        for (int kc = 0; kc < 2; kc++) {
            bf16x8 af[4], bfr[2];
            #pragma unroll
            for (int i = 0; i < 4; i++)
                af[i] = *(const bf16x8*)&As[(wy * 64 + i * 16 + l15) * 64 +
                                            (((kc * 4 + quad) ^ (l15 & 7)) * 8)];
            #pragma unroll
            for (int j = 0; j < 2; j++)
                bfr[j] = *(const bf16x8*)&Bs[(wx * 32 + j * 16 + l15) * 64 +
                                             (((kc * 4 + quad) ^ (l15 & 7)) * 8)];
            #pragma unroll
            for (int i = 0; i < 4; i++)
                #pragma unroll
                for (int j = 0; j < 2; j++)
                    acc[i][j] = __builtin_amdgcn_mfma_f32_16x16x32_bf16(af[i], bfr[j], acc[i][j], 0, 0, 0);
        }
        __syncthreads();
    }

    #pragma unroll
    for (int j = 0; j < 2; j++) {
        const size_t col = col0 + wx * 32 + j * 16 + l15;
        const float bj = bias[col];
        #pragma unroll
        for (int i = 0; i < 4; i++) {
            const size_t row = row0 + wy * 64 + i * 16 + quad * 4;
            #pragma unroll
            for (int r = 0; r < 4; r++)
                Cout[(row + r) * N + col] = acc[i][j][r] + bj;
        }
    }
}

// ---------------------------------------------------------------------------
// Flash attention (S^T = K @ Q^T). R7 structure, PLUS: mask hoisted out of
// the K-loop via per-tile __ballot words held in 2 VGPRs (lane l&15 owns
// tile l&15's 64 bits; in-loop = readlane + bit test). The K-loop now has
// ZERO data-dependent global loads, so the dbuf DMA prefetch keeps its full
// compute phase of slack (previously the in-loop mask loads forced vmcnt(0)
// drains that cancelled the pipeline).
// ---------------------------------------------------------------------------
__global__ __launch_bounds__(256, 4) void attn_mfma(const __bf16* __restrict__ qkv,
                                                    const __bf16* __restrict__ vt,
                                                    const int* __restrict__ mask,
                                                    __bf16* __restrict__ att) {
    __shared__ __align__(16) __bf16 Ks[2][4096];
    __shared__ __align__(16) __bf16 Vs[2][4096];
    __shared__ __align__(16) __bf16 Ps[4][1024];

    const int h  = blockIdx.x & 15;
    const int b  = blockIdx.x >> 4;
    const int qt = 15 - blockIdx.y;  // LPT: longest blocks dispatch first
    const int tid = threadIdx.x, lane = tid & 63, wave = tid >> 6;
    const int l15 = lane & 15, quad = lane >> 4;

    // stage Q (swizzled) through Ks[0]
    #pragma unroll
    for (int i = 0; i < 2; i++) {
        int c = i * 256 + tid;
        int rr = c >> 3, ch = c & 7;
        gload16(&qkv[((size_t)(b * Tt + qt * 64 + rr)) * 3072 + h * 64 + ((ch ^ (rr & 7)) * 8)],
                &Ks[0][c * 8]);
    }

    // mask ballot pass: tile p's 64 bits end up in lane-group (lane&15)==p
    uint32_t mlo = 0, mhi = 0;
    for (int p = 0; p < 16; p++) {
        unsigned long long bal = __ballot(mask[b * Tt + p * 64 + lane] != 0);
        if ((lane & 15) == p) { mlo = (uint32_t)bal; mhi = (uint32_t)(bal >> 32); }
    }

    __syncthreads();
    bf16x8 qf0 = *(const bf16x8*)&Ks[0][(wave * 16 + l15) * 64 + ((quad ^ (l15 & 7)) * 8)];
    bf16x8 qf1 = *(const bf16x8*)&Ks[0][(wave * 16 + l15) * 64 + (((4 + quad) ^ (l15 & 7)) * 8)];
    __syncthreads();  // Q frag reads done -> Ks[0] reusable

    #pragma unroll
    for (int i = 0; i < 2; i++) {
        int c = i * 256 + tid;
        int rr = c >> 3, ch = c & 7, sw = ((ch ^ (rr & 7)) * 8);
        gload16(&qkv[((size_t)(b * Tt + rr)) * 3072 + 1024 + h * 64 + sw], &Ks[0][c * 8]);
        gload16(&vt[((size_t)((b * Hh + h) * 64 + rr)) * Tt + sw], &Vs[0][c * 8]);
    }

    f32x4 Oacc[4] = {};
    float lsum = 0.0f;

    for (int kt = 0; kt <= qt; kt++) {
        __syncthreads();  // DMA(kt) complete (issued a full compute phase ago)
        const int cur = kt & 1;
        if (kt < qt) {
            #pragma unroll
            for (int i = 0; i < 2; i++) {
                int c = i * 256 + tid;
                int rr = c >> 3, ch = c & 7, sw = ((ch ^ (rr & 7)) * 8);
                gload16(&qkv[((size_t)(b * Tt + (kt + 1) * 64 + rr)) * 3072 + 1024 + h * 64 + sw],
                        &Ks[cur ^ 1][c * 8]);
                gload16(&vt[((size_t)((b * Hh + h) * 64 + rr)) * Tt + (kt + 1) * 64 + sw],
                        &Vs[cur ^ 1][c * 8]);
            }
        }

        // mask bits for this tile (uniform readlane, no memory access)
        const uint32_t lo = (uint32_t)__builtin_amdgcn_readlane((int)mlo, kt);
        const uint32_t hi = (uint32_t)__builtin_amdgcn_readlane((int)mhi, kt);

        bf16x8 ak[4][2];
        #pragma unroll
        for (int j = 0; j < 4; j++)
            #pragma unroll
            for (int kc = 0; kc < 2; kc++)
                ak[j][kc] = *(const bf16x8*)&Ks[cur][(j * 16 + l15) * 64 +
                                                     (((kc * 4 + quad) ^ (l15 & 7)) * 8)];
        #pragma unroll
        for (int j = 0; j < 4; j++) {
            f32x4 st = {};
            st = __builtin_amdgcn_mfma_f32_16x16x32_bf16(ak[j][0], qf0, st, 0, 0, 0);
            st = __builtin_amdgcn_mfma_f32_16x16x32_bf16(ak[j][1], qf1, st, 0, 0, 0);
            const uint32_t fld = (j < 2) ? (lo >> (j * 16)) : (hi >> ((j - 2) * 16));
            bf16x4 pv;
            #pragma unroll
            for (int r = 0; r < 4; r++) {
                const int tloc = j * 16 + quad * 4 + r;
                bool keep = (fld >> (quad * 4 + r)) & 1;
                if (kt == qt) keep = keep && (tloc <= wave * 16 + l15);
                const float pe = keep ? __expf(st[r]) : 0.0f;
                lsum += pe;
                pv[r] = (__bf16)pe;
            }
            *(bf16x4*)&Ps[wave][l15 * 64 + (((j * 4 + quad) ^ ((l15 & 7) << 1)) * 4)] = pv;
        }

        bf16x8 av[4][2];
        #pragma unroll
        for (int n = 0; n < 4; n++)
            #pragma unroll
            for (int kc = 0; kc < 2; kc++)
                av[n][kc] = *(const bf16x8*)&Vs[cur][(n * 16 + l15) * 64 +
                                                     (((kc * 4 + quad) ^ (l15 & 7)) * 8)];
        bf16x8 p0 = *(const bf16x8*)&Ps[wave][l15 * 64 + (((2 * quad) ^ ((l15 & 7) << 1)) * 4)];
        bf16x8 p1 = *(const bf16x8*)&Ps[wave][l15 * 64 + (((2 * (4 + quad)) ^ ((l15 & 7) << 1)) * 4)];
        #pragma unroll
        for (int n = 0; n < 4; n++) {
            Oacc[n] = __builtin_amdgcn_mfma_f32_16x16x32_bf16(av[n][0], p0, Oacc[n], 0, 0, 0);
            Oacc[n] = __builtin_amdgcn_mfma_f32_16x16x32_bf16(av[n][1], p1, Oacc[n], 0, 0, 0);
        }
    }

    float lt = lsum;
    lt += __shfl_xor(lt, 16);
    lt += __shfl_xor(lt, 32);
    const float inv = 1.0f / lt;
    const int q = qt * 64 + wave * 16 + l15;
    #pragma unroll
    for (int n = 0; n < 4; n++) {
        bf16x4 o;
        #pragma unroll
        for (int r = 0; r < 4; r++) o[r] = (__bf16)(Oacc[n][r] * inv);
        *(bf16x4*)&att[((size_t)(b * Tt + q)) * Dd + h * 64 + n * 16 + quad * 4] = o;
    }
}

// ---------------------------------------------------------------------------
extern "C" void kernel_launch(void* const* d_in, const int* in_sizes, int n_in,
                              void* d_out, int out_size, void* d_ws, size_t ws_size,
                              hipStream_t stream) {
    const float* x     = (const float*)d_in[0];
    const float* Wqkv  = (const float*)d_in[1];
    const float* bqkv  = (const float*)d_in[2];
    const float* Wproj = (const float*)d_in[3];
    const float* bproj = (const float*)d_in[4];
    const int*   mask  = (const int*)d_in[5];
    float* out = (float*)d_out;

    __bf16* xb  = (__bf16*)d_ws;                         // 4096*1024
    __bf16* wqT = xb  + (size_t)4096 * 1024;             // 3072*1024
    __bf16* wpT = wqT + (size_t)3072 * 1024;             // 1024*1024
    __bf16* qkv = wpT + (size_t)1024 * 1024;             // 4096*3072
    __bf16* vt  = qkv + (size_t)4096 * 3072;             // 4*16*64*1024
    __bf16* att = vt  + (size_t)4 * 16 * 64 * 1024;      // 4096*1024

    prep<<<4096 + 768 + 256, 256, 0, stream>>>(x, Wqkv, Wproj, xb, wqT, wpT);

    gemm_qkv<<<dim3(24, 32), 256, 0, stream>>>(xb, wqT, bqkv, qkv, vt, 4096, 3072, 1024);

    attn_mfma<<<dim3(64, 16), 256, 0, stream>>>(qkv, vt, mask, att);

    gemm_bf16_n64<<<dim3(16, 32), 256, 0, stream>>>(att, wpT, bproj, out, 4096, 1024, 1024);
}